// Round 7
// baseline (391.092 us; speedup 1.0000x reference)
//
#include <hip/hip_runtime.h>
#include <hip/hip_fp16.h>
#include <math.h>

#define BB   32
#define TT   12
#define NNODE 325
#define BN   (BB * NNODE)   // 10400
#define BNP  10496          // BN padded to multiple of 128
#define EE   96
#define LHH  128
#define HH   64
#define OUTT 12
#define XC   97             // 1 + E channels in x

typedef _Float16 f16;
typedef __attribute__((ext_vector_type(2))) _Float16 f16x2;
typedef __attribute__((ext_vector_type(8))) _Float16 f16x8;
typedef __attribute__((ext_vector_type(4))) float f32x4;

#define GLOAD16(g, l) __builtin_amdgcn_global_load_lds(                        \
    (const __attribute__((address_space(1))) void*)(g),                        \
    (__attribute__((address_space(3))) void*)(l), 16, 0, 0)

#if __has_builtin(__builtin_amdgcn_fdot2)
#define FDOT2(a, b, c) __builtin_amdgcn_fdot2((a), (b), (c), false)
#else
static __device__ inline float FDOT2(f16x2 a, f16x2 b, float c) {
    return c + (float)a[0] * (float)b[0] + (float)a[1] * (float)b[1];
}
#endif

static __device__ inline float fast_sig(float z) {
    return 1.f / (1.f + __expf(-z));
}
static __device__ inline float fast_tanh(float z) {
    return 2.f / (1.f + __expf(-2.f * z)) - 1.f;
}

// whbuf column permutation: original col c = h*64+k  ->  col' = (h>>3)*512 + k*8 + (h&7)
__device__ __host__ inline int wh_perm(int c) {
    return ((c >> 9) << 9) + ((c & 63) << 3) + ((c >> 6) & 7);
}
__device__ inline int wh_perm_inv(int p) {
    int j = p >> 9, k = (p >> 3) & 63, e = p & 7;
    return (j * 8 + e) * 64 + k;
}

// ---------------------------------------------------------------------------
// K1: meta2[row][e(128 padded)] = fp16(mean_t x[b][t][n][1+e]); pads zeroed
// ---------------------------------------------------------------------------
__global__ void meta2_kernel(const float* __restrict__ x, f16* __restrict__ meta2) {
    int idx = blockIdx.x * 256 + threadIdx.x;
    if (idx >= BNP * 128) return;
    int e = idx & 127, row = idx >> 7;
    float s = 0.f;
    if (row < BN && e < EE) {
        int b = row / NNODE, n = row - b * NNODE;
        const float* px = x + ((size_t)b * TT * NNODE + n) * XC + 1 + e;
#pragma unroll
        for (int t = 0; t < TT; ++t) s += px[(size_t)t * NNODE * XC];
        s *= (1.0f / 12.0f);
    }
    meta2[idx] = (f16)s;
}

// ---------------------------------------------------------------------------
// K2: merged prep (B1t[1536][128] K-padded, bias1, b2s, bias2s) + b2t build
// ---------------------------------------------------------------------------
__global__ void prep_b2t_kernel(const float* __restrict__ wx1, const float* __restrict__ wx1b,
                                const float* __restrict__ wx2, const float* __restrict__ wx2b,
                                const float* __restrict__ wh1, const float* __restrict__ wh1b,
                                const float* __restrict__ b1,  const float* __restrict__ b1b,
                                const float* __restrict__ b2,  const float* __restrict__ b2b,
                                const float* __restrict__ wh2,
                                f16* __restrict__ B1t, float* __restrict__ bias1,
                                f16* __restrict__ b2s, float* __restrict__ bias2s,
                                f16* __restrict__ b2t) {
    __shared__ float tile[64][65];
    int bx = blockIdx.x;
    if (bx < 1032) {
        int idx = bx * 256 + threadIdx.x;
        if (idx < 196608) {                   // B1t[c][k] (k<96 real, else 0)
            int c = idx >> 7, k = idx & 127;
            int net = c >> 9, g = (c >> 7) & 3, l = c & 127;
            const float* w = (net == 0) ? wx1 : ((net == 1) ? wh1 : b1);
            B1t[idx] = (k < 96) ? (f16)w[(size_t)g * 12288 + k * 128 + l] : (f16)0.f;
            return;
        }
        idx -= 196608;
        if (idx < 1536) {
            int net = idx >> 9, g = (idx >> 7) & 3, l = idx & 127;
            const float* wb = (net == 0) ? wx1b : ((net == 1) ? wh1b : b1b);
            bias1[idx] = wb[g * 128 + l];
            return;
        }
        idx -= 1536;
        if (idx < 65536) {                    // b2s[combo][cc][k]
            int combo = idx >> 13, rem = idx & 8191, cc = rem >> 7, k = rem & 127;
            int a = combo >> 2, g = combo & 3;
            const float* w = a ? b2 : wx2;
            b2s[idx] = (f16)w[(size_t)g * 8192 + k * 64 + cc];
            return;
        }
        idx -= 65536;
        if (idx < 512) {
            int combo = idx >> 6, cc = idx & 63;
            int a = combo >> 2, g = combo & 3;
            bias2s[idx] = (a ? b2b : wx2b)[g * 64 + cc];
        }
        return;
    }
    // b2t part: b2t[g][wh_perm(col)][k] = fp16(wh2[g][k][col])
    int bid = bx - 1032;
    int g = bid >> 7, l0 = ((bid >> 6) & 1) * 64, c0 = (bid & 63) * 64;
    for (int i = threadIdx.x; i < 64 * 64; i += 256) {
        int rl = i >> 6, cc = i & 63;
        tile[rl][cc] = wh2[(size_t)(g * 128 + l0 + rl) * 4096 + c0 + cc];
    }
    __syncthreads();
    for (int i = threadIdx.x; i < 64 * 64; i += 256) {
        int cl = i >> 6, ll = i & 63;
        int colp = wh_perm(c0 + cl);
        b2t[((size_t)g * 4096 + colp) * 128 + l0 + ll] = (f16)tile[ll][cl];
    }
}

// ---------------------------------------------------------------------------
// K3: single-stage stage-1 GEMM (K=128 padded): hdn_all = relu(meta2 @ B1t^T + b)
// ---------------------------------------------------------------------------
__global__ __launch_bounds__(256) void stage1_gemm(const f16* __restrict__ meta2,
                                                   const f16* __restrict__ B1t,
                                                   const float* __restrict__ bias1,
                                                   f16* __restrict__ hdn_all) {
    __shared__ f16 smem[32768];              // As 16K f16 | Bs 16K f16 ; outT reuse
    f16* As = smem;
    f16* Bs = smem + 16384;
    int c0 = blockIdx.x * 128, r0 = blockIdx.y * 128;
    int tid = threadIdx.x, w = tid >> 6;
    const f16* Ag = meta2 + (size_t)r0 * 128;
    const f16* Bg = B1t + (size_t)c0 * 128;
    int srow = tid >> 4;
    int scol = ((tid & 15) ^ (srow & 15)) << 3;
#pragma unroll
    for (int j = 0; j < 8; ++j)
        GLOAD16(Ag + (size_t)(j * 16 + srow) * 128 + scol, As + j * 2048 + w * 512);
#pragma unroll
    for (int j = 0; j < 8; ++j)
        GLOAD16(Bg + (size_t)(j * 16 + srow) * 128 + scol, Bs + j * 2048 + w * 512);

    int l = tid & 63, wr = w >> 1, wc = w & 1, lr = l & 15, hk = l >> 4;
    const f16 *ar[4], *br[4];
#pragma unroll
    for (int m = 0; m < 4; ++m) ar[m] = As + (wr * 64 + m * 16 + lr) * 128;
#pragma unroll
    for (int n = 0; n < 4; ++n) br[n] = Bs + (wc * 64 + n * 16 + lr) * 128;

    f32x4 acc[4][4];
#pragma unroll
    for (int m = 0; m < 4; ++m)
#pragma unroll
        for (int n = 0; n < 4; ++n) acc[m][n] = (f32x4){0.f, 0.f, 0.f, 0.f};

    __syncthreads();
#pragma unroll
    for (int kk = 0; kk < 4; ++kk) {
        int so = (((kk * 4 + hk) ^ lr) << 3);
        f16x8 a[4], b[4];
#pragma unroll
        for (int m = 0; m < 4; ++m) a[m] = *(const f16x8*)(ar[m] + so);
#pragma unroll
        for (int n = 0; n < 4; ++n) b[n] = *(const f16x8*)(br[n] + so);
#pragma unroll
        for (int m = 0; m < 4; ++m)
#pragma unroll
            for (int n = 0; n < 4; ++n)
                acc[m][n] = __builtin_amdgcn_mfma_f32_16x16x32_f16(a[m], b[n], acc[m][n], 0, 0, 0);
    }
    float bias[4];
#pragma unroll
    for (int n = 0; n < 4; ++n) bias[n] = bias1[c0 + wc * 64 + n * 16 + lr];
    __syncthreads();
    f16* outT = smem;                         // [128][136]
#pragma unroll
    for (int m = 0; m < 4; ++m)
#pragma unroll
        for (int reg = 0; reg < 4; ++reg) {
            int rowL = wr * 64 + m * 16 + hk * 4 + reg;
#pragma unroll
            for (int n = 0; n < 4; ++n)
                outT[rowL * 136 + wc * 64 + n * 16 + lr] =
                    (f16)fmaxf(acc[m][n][reg] + bias[n], 0.f);
        }
    __syncthreads();
#pragma unroll
    for (int pass = 0; pass < 8; ++pass) {
        int rowL = pass * 16 + (tid >> 4);
        int sc = (tid & 15) << 3;
        f16x8 v = *(const f16x8*)(outT + rowL * 136 + sc);
        *(f16x8*)(hdn_all + (size_t)(r0 + rowL) * 1536 + c0 + sc) = v;
    }
}

// ---------------------------------------------------------------------------
// K4: single-stage Wh GEMM (K=128) into permuted whbuf. grid (32, ceil/128, 4)
// ---------------------------------------------------------------------------
__global__ __launch_bounds__(256) void gemm_wh_mfma(const f16* __restrict__ hdn_all,
                                                    const f16* __restrict__ b2t,
                                                    const float* __restrict__ wh2b,
                                                    f16* __restrict__ whbuf,
                                                    int chunk0, int chunkrows) {
    __shared__ f16 smem[32768];
    f16* As = smem;
    f16* Bs = smem + 16384;
    int g = blockIdx.z, col0 = blockIdx.x * 128, r0 = blockIdx.y * 128;
    int tid = threadIdx.x, w = tid >> 6;
    const f16* Ag = hdn_all + (size_t)(chunk0 + r0) * 1536 + 512 + g * 128;
    const f16* Bg = b2t + ((size_t)g * 4096 + col0) * 128;
    int srow = tid >> 4;
    int scol = ((tid & 15) ^ (srow & 15)) << 3;
#pragma unroll
    for (int j = 0; j < 8; ++j)
        GLOAD16(Ag + (size_t)(j * 16 + srow) * 1536 + scol, As + j * 2048 + w * 512);
#pragma unroll
    for (int j = 0; j < 8; ++j)
        GLOAD16(Bg + (size_t)(j * 16 + srow) * 128 + scol, Bs + j * 2048 + w * 512);

    int l = tid & 63, wr = w >> 1, wc = w & 1, lr = l & 15, hk = l >> 4;
    const f16 *ar[4], *br[4];
#pragma unroll
    for (int m = 0; m < 4; ++m) ar[m] = As + (wr * 64 + m * 16 + lr) * 128;
#pragma unroll
    for (int n = 0; n < 4; ++n) br[n] = Bs + (wc * 64 + n * 16 + lr) * 128;

    f32x4 acc[4][4];
#pragma unroll
    for (int m = 0; m < 4; ++m)
#pragma unroll
        for (int n = 0; n < 4; ++n) acc[m][n] = (f32x4){0.f, 0.f, 0.f, 0.f};

    __syncthreads();
#pragma unroll
    for (int kk = 0; kk < 4; ++kk) {
        int so = (((kk * 4 + hk) ^ lr) << 3);
        f16x8 a[4], b[4];
#pragma unroll
        for (int m = 0; m < 4; ++m) a[m] = *(const f16x8*)(ar[m] + so);
#pragma unroll
        for (int n = 0; n < 4; ++n) b[n] = *(const f16x8*)(br[n] + so);
#pragma unroll
        for (int m = 0; m < 4; ++m)
#pragma unroll
            for (int n = 0; n < 4; ++n)
                acc[m][n] = __builtin_amdgcn_mfma_f32_16x16x32_f16(a[m], b[n], acc[m][n], 0, 0, 0);
    }
    float bias[4];
#pragma unroll
    for (int n = 0; n < 4; ++n) {
        int colp = col0 + wc * 64 + n * 16 + lr;
        bias[n] = wh2b[g * 4096 + wh_perm_inv(colp)];
    }
    __syncthreads();
    f16* outT = smem;                         // [128][136]
#pragma unroll
    for (int m = 0; m < 4; ++m)
#pragma unroll
        for (int reg = 0; reg < 4; ++reg) {
            int rowL = wr * 64 + m * 16 + hk * 4 + reg;
#pragma unroll
            for (int n = 0; n < 4; ++n)
                outT[rowL * 136 + wc * 64 + n * 16 + lr] = (f16)(acc[m][n][reg] + bias[n]);
        }
    __syncthreads();
#pragma unroll
    for (int pass = 0; pass < 8; ++pass) {
        int rowL = pass * 16 + (tid >> 4);
        int row = r0 + rowL;
        if (row < chunkrows) {
            int sc = (tid & 15) << 3;
            f16x8 v = *(const f16x8*)(outT + rowL * 136 + sc);
            *(f16x8*)(whbuf + ((size_t)row * 4 + g) * 4096 + col0 + sc) = v;
        }
    }
}

// ---------------------------------------------------------------------------
// K5: single-stage batched stage-2 GEMMs: wxbb[combo][row][64]. grid (82, 8)
// ---------------------------------------------------------------------------
__global__ __launch_bounds__(256) void stage2s_gemm(const f16* __restrict__ hdn_all,
                                                    const f16* __restrict__ b2s,
                                                    const float* __restrict__ bias2s,
                                                    float* __restrict__ wxbb) {
    __shared__ f16 smem[24576];               // As 16K | Bs 8K
    f16* As = smem;
    f16* Bs = smem + 16384;
    int combo = blockIdx.y, r0 = blockIdx.x * 128;
    int a = combo >> 2, g = combo & 3;
    int aoff = (a ? 1024 : 0) + g * 128;
    int tid = threadIdx.x, w = tid >> 6;
    const f16* Ag = hdn_all + (size_t)r0 * 1536 + aoff;
    const f16* Bg = b2s + (size_t)combo * 8192;
    int srow = tid >> 4;
    int scol = ((tid & 15) ^ (srow & 15)) << 3;
#pragma unroll
    for (int j = 0; j < 8; ++j)
        GLOAD16(Ag + (size_t)(j * 16 + srow) * 1536 + scol, As + j * 2048 + w * 512);
#pragma unroll
    for (int j = 0; j < 4; ++j)
        GLOAD16(Bg + (size_t)(j * 16 + srow) * 128 + scol, Bs + j * 2048 + w * 512);

    int l = tid & 63, lr = l & 15, hk = l >> 4;
    const f16 *ar[2], *br[4];
#pragma unroll
    for (int m = 0; m < 2; ++m) ar[m] = As + (w * 32 + m * 16 + lr) * 128;
#pragma unroll
    for (int n = 0; n < 4; ++n) br[n] = Bs + (n * 16 + lr) * 128;

    f32x4 acc[2][4];
#pragma unroll
    for (int m = 0; m < 2; ++m)
#pragma unroll
        for (int n = 0; n < 4; ++n) acc[m][n] = (f32x4){0.f, 0.f, 0.f, 0.f};

    __syncthreads();
#pragma unroll
    for (int kk = 0; kk < 4; ++kk) {
        int so = (((kk * 4 + hk) ^ lr) << 3);
        f16x8 av[2], bv[4];
#pragma unroll
        for (int m = 0; m < 2; ++m) av[m] = *(const f16x8*)(ar[m] + so);
#pragma unroll
        for (int n = 0; n < 4; ++n) bv[n] = *(const f16x8*)(br[n] + so);
#pragma unroll
        for (int m = 0; m < 2; ++m)
#pragma unroll
            for (int n = 0; n < 4; ++n)
                acc[m][n] = __builtin_amdgcn_mfma_f32_16x16x32_f16(av[m], bv[n], acc[m][n], 0, 0, 0);
    }
    float bias[4];
#pragma unroll
    for (int n = 0; n < 4; ++n) bias[n] = bias2s[combo * 64 + n * 16 + lr];
#pragma unroll
    for (int m = 0; m < 2; ++m)
#pragma unroll
        for (int reg = 0; reg < 4; ++reg) {
            int row = r0 + w * 32 + m * 16 + hk * 4 + reg;
            if (row < BN) {
#pragma unroll
                for (int n = 0; n < 4; ++n) {
                    int col = n * 16 + lr;
                    wxbb[((size_t)combo * BN + row) * 64 + col] = acc[m][n][reg] + bias[n];
                }
            }
        }
}

// ---------------------------------------------------------------------------
// K6: wave-per-row LSTM + head (zero barriers, fdot2, fast activations)
// ---------------------------------------------------------------------------
__global__ __launch_bounds__(256) void lstm_head_kernel(const f16* __restrict__ whbuf,
                                                        const float* __restrict__ wxbb,
                                                        const float* __restrict__ x,
                                                        const float* __restrict__ fc1,
                                                        const float* __restrict__ fc1b,
                                                        const float* __restrict__ fc2,
                                                        const float* __restrict__ fc2b,
                                                        float* __restrict__ out,
                                                        int chunk0, int chunkrows) {
    __shared__ __align__(16) f16 hs[4][64];
    __shared__ float xts[4][TT];
    __shared__ float a1s[4][32];
    int w = threadIdx.x >> 6, lane = threadIdx.x & 63;
    int r = blockIdx.x * 4 + w;
    if (r >= chunkrows) return;
    int row = chunk0 + r;
    int b = row / NNODE, n = row - b * NNODE;
    int k = lane;

    const f16* wp = whbuf + ((size_t)r * 4) * 4096 + k * 8;
    f16x8 wh[4][8];
#pragma unroll
    for (int g = 0; g < 4; ++g)
#pragma unroll
        for (int jj = 0; jj < 8; ++jj)
            wh[g][jj] = *(const f16x8*)(wp + (size_t)g * 4096 + jj * 512);

    float wxv[4], bbv[4];
#pragma unroll
    for (int g = 0; g < 4; ++g) {
        wxv[g] = wxbb[((size_t)g * BN + row) * HH + k];
        bbv[g] = wxbb[((size_t)(4 + g) * BN + row) * HH + k];
    }
    if (lane < TT) xts[w][lane] = x[((size_t)b * TT + lane) * NNODE * XC + (size_t)n * XC];
    hs[w][k] = (f16)0.f;

    float c = 0.f;
    for (int t = 0; t < TT; ++t) {
        float xt = xts[w][t];
        float z0 = wxv[0] * xt + bbv[0];
        float z1 = wxv[1] * xt + bbv[1];
        float z2 = wxv[2] * xt + bbv[2];
        float z3 = wxv[3] * xt + bbv[3];
#pragma unroll
        for (int jj = 0; jj < 8; ++jj) {
            f16x8 hv = ((const f16x8*)hs[w])[jj];
#pragma unroll
            for (int p = 0; p < 4; ++p) {
                f16x2 hp = {hv[2 * p], hv[2 * p + 1]};
                f16x2 w0 = {wh[0][jj][2 * p], wh[0][jj][2 * p + 1]};
                f16x2 w1 = {wh[1][jj][2 * p], wh[1][jj][2 * p + 1]};
                f16x2 w2 = {wh[2][jj][2 * p], wh[2][jj][2 * p + 1]};
                f16x2 w3 = {wh[3][jj][2 * p], wh[3][jj][2 * p + 1]};
                z0 = FDOT2(w0, hp, z0);
                z1 = FDOT2(w1, hp, z1);
                z2 = FDOT2(w2, hp, z2);
                z3 = FDOT2(w3, hp, z3);
            }
        }
        float gg = fast_tanh(z0);
        float ii = fast_sig(z1);
        float ff = fast_sig(z2);
        float oo = fast_sig(z3);
        c = gg * ii + c * ff;
        hs[w][k] = (f16)(fast_tanh(c) * oo);
    }
    if (lane < 32) {
        float s = fc1b[lane];
#pragma unroll
        for (int h = 0; h < 64; ++h)
            s += fmaxf((float)hs[w][h], 0.f) * fc1[h * 32 + lane];
        a1s[w][lane] = fmaxf(s, 0.f);
    }
    if (lane < OUTT) {
        float s = fc2b[lane];
#pragma unroll
        for (int j = 0; j < 32; ++j) s += a1s[w][j] * fc2[j * OUTT + lane];
        out[((size_t)b * OUTT + lane) * NNODE + n] = s;
    }
}

// ---------------------------------------------------------------------------
extern "C" void kernel_launch(void* const* d_in, const int* in_sizes, int n_in,
                              void* d_out, int out_size, void* d_ws, size_t ws_size,
                              hipStream_t stream) {
    (void)in_sizes; (void)n_in; (void)out_size;
    const float* x    = (const float*)d_in[0];
    const float* wx1  = (const float*)d_in[1];
    const float* wx1b = (const float*)d_in[2];
    const float* wx2  = (const float*)d_in[3];
    const float* wx2b = (const float*)d_in[4];
    const float* wh1  = (const float*)d_in[5];
    const float* wh1b = (const float*)d_in[6];
    const float* wh2  = (const float*)d_in[7];
    const float* wh2b = (const float*)d_in[8];
    const float* b1   = (const float*)d_in[9];
    const float* b1b  = (const float*)d_in[10];
    const float* b2   = (const float*)d_in[11];
    const float* b2b  = (const float*)d_in[12];
    const float* fc1  = (const float*)d_in[13];
    const float* fc1b = (const float*)d_in[14];
    const float* fc2  = (const float*)d_in[15];
    const float* fc2b = (const float*)d_in[16];
    float* out = (float*)d_out;
    float* ws  = (float*)d_ws;

    float* bias1  = ws;                              // 1,536 f
    float* bias2s = bias1 + 1536;                    // 512 f
    float* wxbb   = bias2s + 512;                    // 5,324,800 f
    f16* meta2    = (f16*)(wxbb + 5324800);          // BNP*128 = 1,343,488
    f16* B1t      = meta2 + (size_t)BNP * 128;       // 196,608
    f16* hdn_all  = B1t + 196608;                    // BNP*1536
    f16* b2t      = hdn_all + (size_t)BNP * 1536;    // 4*4096*128
    f16* b2s      = b2t + (size_t)4 * 4096 * 128;    // 65,536
    f16* whbuf    = b2s + 65536;                     // chunk*16384 (reused per chunk)

    const size_t fixedB = (size_t)(1536 + 512 + 5324800) * 4
        + ((size_t)BNP * 128 + 196608 + (size_t)BNP * 1536
           + (size_t)4 * 4096 * 128 + 65536) * 2;
    size_t availB = (ws_size > fixedB) ? (ws_size - fixedB) : 0;
    long long ch = (long long)(availB / (16384 * 2));
    // L3-tiling: keep whbuf (chunk*32KB) Infinity-Cache-resident so the
    // gemm->lstm round trip never touches HBM. 1792 rows = 58.7 MB.
    if (ch > 1792) ch = 1792;
    if (ch < 128)  ch = 128;
    int chunk = (int)(ch & ~127LL);

    meta2_kernel<<<(BNP * 128 + 255) / 256, 256, 0, stream>>>(x, meta2);
    prep_b2t_kernel<<<1544, 256, 0, stream>>>(wx1, wx1b, wx2, wx2b, wh1, wh1b,
                                              b1, b1b, b2, b2b, wh2,
                                              B1t, bias1, b2s, bias2s, b2t);
    stage1_gemm<<<dim3(12, BNP / 128), 256, 0, stream>>>(meta2, B1t, bias1, hdn_all);
    stage2s_gemm<<<dim3(BNP / 128, 8), 256, 0, stream>>>(hdn_all, b2s, bias2s, wxbb);
    for (int c0 = 0; c0 < BN; c0 += chunk) {
        int cr = BN - c0;
        if (cr > chunk) cr = chunk;
        gemm_wh_mfma<<<dim3(32, (cr + 127) / 128, 4), 256, 0, stream>>>(
            hdn_all, b2t, wh2b, whbuf, c0, cr);
        lstm_head_kernel<<<(cr + 3) / 4, 256, 0, stream>>>(whbuf, wxbb, x, fc1, fc1b,
                                                           fc2, fc2b, out, c0, cr);
    }
}

// Round 8
// 332.152 us; speedup vs baseline: 1.1775x; 1.1775x over previous
//
#include <hip/hip_runtime.h>
#include <hip/hip_fp16.h>
#include <math.h>

#define BB   32
#define TT   12
#define NNODE 325
#define BN   (BB * NNODE)   // 10400
#define BNP  10496          // BN padded to multiple of 128
#define EE   96
#define LHH  128
#define HH   64
#define OUTT 12
#define XC   97             // 1 + E channels in x

typedef _Float16 f16;
typedef __attribute__((ext_vector_type(2))) _Float16 f16x2;
typedef __attribute__((ext_vector_type(8))) _Float16 f16x8;
typedef __attribute__((ext_vector_type(4))) float f32x4;

#define GLOAD16(g, l) __builtin_amdgcn_global_load_lds(                        \
    (const __attribute__((address_space(1))) void*)(g),                        \
    (__attribute__((address_space(3))) void*)(l), 16, 0, 0)

#if __has_builtin(__builtin_amdgcn_fdot2)
#define FDOT2(a, b, c) __builtin_amdgcn_fdot2((a), (b), (c), false)
#else
static __device__ inline float FDOT2(f16x2 a, f16x2 b, float c) {
    return c + (float)a[0] * (float)b[0] + (float)a[1] * (float)b[1];
}
#endif

static __device__ inline float fast_sig(float z) {
    return 1.f / (1.f + __expf(-z));
}
static __device__ inline float fast_tanh(float z) {
    return 2.f / (1.f + __expf(-2.f * z)) - 1.f;
}

// whbuf column permutation: original col c = h*64+k  ->  col' = (h>>3)*512 + k*8 + (h&7)
__device__ __host__ inline int wh_perm(int c) {
    return ((c >> 9) << 9) + ((c & 63) << 3) + ((c >> 6) & 7);
}
__device__ inline int wh_perm_inv(int p) {
    int j = p >> 9, k = (p >> 3) & 63, e = p & 7;
    return (j * 8 + e) * 64 + k;
}

// ---------------------------------------------------------------------------
// K1: meta2[row][e(128 padded)] = fp16(mean_t x[b][t][n][1+e]); pads zeroed
// ---------------------------------------------------------------------------
__global__ void meta2_kernel(const float* __restrict__ x, f16* __restrict__ meta2) {
    int idx = blockIdx.x * 256 + threadIdx.x;
    if (idx >= BNP * 128) return;
    int e = idx & 127, row = idx >> 7;
    float s = 0.f;
    if (row < BN && e < EE) {
        int b = row / NNODE, n = row - b * NNODE;
        const float* px = x + ((size_t)b * TT * NNODE + n) * XC + 1 + e;
#pragma unroll
        for (int t = 0; t < TT; ++t) s += px[(size_t)t * NNODE * XC];
        s *= (1.0f / 12.0f);
    }
    meta2[idx] = (f16)s;
}

// ---------------------------------------------------------------------------
// K2: merged prep (B1t[1536][128] K-padded, bias1, b2s, bias2s) + b2t build
// ---------------------------------------------------------------------------
__global__ void prep_b2t_kernel(const float* __restrict__ wx1, const float* __restrict__ wx1b,
                                const float* __restrict__ wx2, const float* __restrict__ wx2b,
                                const float* __restrict__ wh1, const float* __restrict__ wh1b,
                                const float* __restrict__ b1,  const float* __restrict__ b1b,
                                const float* __restrict__ b2,  const float* __restrict__ b2b,
                                const float* __restrict__ wh2,
                                f16* __restrict__ B1t, float* __restrict__ bias1,
                                f16* __restrict__ b2s, float* __restrict__ bias2s,
                                f16* __restrict__ b2t) {
    __shared__ float tile[64][65];
    int bx = blockIdx.x;
    if (bx < 1032) {
        int idx = bx * 256 + threadIdx.x;
        if (idx < 196608) {                   // B1t[c][k] (k<96 real, else 0)
            int c = idx >> 7, k = idx & 127;
            int net = c >> 9, g = (c >> 7) & 3, l = c & 127;
            const float* w = (net == 0) ? wx1 : ((net == 1) ? wh1 : b1);
            B1t[idx] = (k < 96) ? (f16)w[(size_t)g * 12288 + k * 128 + l] : (f16)0.f;
            return;
        }
        idx -= 196608;
        if (idx < 1536) {
            int net = idx >> 9, g = (idx >> 7) & 3, l = idx & 127;
            const float* wb = (net == 0) ? wx1b : ((net == 1) ? wh1b : b1b);
            bias1[idx] = wb[g * 128 + l];
            return;
        }
        idx -= 1536;
        if (idx < 65536) {                    // b2s[combo][cc][k]
            int combo = idx >> 13, rem = idx & 8191, cc = rem >> 7, k = rem & 127;
            int a = combo >> 2, g = combo & 3;
            const float* w = a ? b2 : wx2;
            b2s[idx] = (f16)w[(size_t)g * 8192 + k * 64 + cc];
            return;
        }
        idx -= 65536;
        if (idx < 512) {
            int combo = idx >> 6, cc = idx & 63;
            int a = combo >> 2, g = combo & 3;
            bias2s[idx] = (a ? b2b : wx2b)[g * 64 + cc];
        }
        return;
    }
    // b2t part: b2t[g][wh_perm(col)][k] = fp16(wh2[g][k][col])
    int bid = bx - 1032;
    int g = bid >> 7, l0 = ((bid >> 6) & 1) * 64, c0 = (bid & 63) * 64;
    for (int i = threadIdx.x; i < 64 * 64; i += 256) {
        int rl = i >> 6, cc = i & 63;
        tile[rl][cc] = wh2[(size_t)(g * 128 + l0 + rl) * 4096 + c0 + cc];
    }
    __syncthreads();
    for (int i = threadIdx.x; i < 64 * 64; i += 256) {
        int cl = i >> 6, ll = i & 63;
        int colp = wh_perm(c0 + cl);
        b2t[((size_t)g * 4096 + colp) * 128 + l0 + ll] = (f16)tile[ll][cl];
    }
}

// ---------------------------------------------------------------------------
// K3: single-stage stage-1 GEMM (K=128 padded): hdn_all = relu(meta2 @ B1t^T + b)
// ---------------------------------------------------------------------------
__global__ __launch_bounds__(256) void stage1_gemm(const f16* __restrict__ meta2,
                                                   const f16* __restrict__ B1t,
                                                   const float* __restrict__ bias1,
                                                   f16* __restrict__ hdn_all) {
    __shared__ f16 smem[32768];              // As 16K f16 | Bs 16K f16 ; outT reuse
    f16* As = smem;
    f16* Bs = smem + 16384;
    int c0 = blockIdx.x * 128, r0 = blockIdx.y * 128;
    int tid = threadIdx.x, w = tid >> 6;
    const f16* Ag = meta2 + (size_t)r0 * 128;
    const f16* Bg = B1t + (size_t)c0 * 128;
    int srow = tid >> 4;
    int scol = ((tid & 15) ^ (srow & 15)) << 3;
#pragma unroll
    for (int j = 0; j < 8; ++j)
        GLOAD16(Ag + (size_t)(j * 16 + srow) * 128 + scol, As + j * 2048 + w * 512);
#pragma unroll
    for (int j = 0; j < 8; ++j)
        GLOAD16(Bg + (size_t)(j * 16 + srow) * 128 + scol, Bs + j * 2048 + w * 512);

    int l = tid & 63, wr = w >> 1, wc = w & 1, lr = l & 15, hk = l >> 4;
    const f16 *ar[4], *br[4];
#pragma unroll
    for (int m = 0; m < 4; ++m) ar[m] = As + (wr * 64 + m * 16 + lr) * 128;
#pragma unroll
    for (int n = 0; n < 4; ++n) br[n] = Bs + (wc * 64 + n * 16 + lr) * 128;

    f32x4 acc[4][4];
#pragma unroll
    for (int m = 0; m < 4; ++m)
#pragma unroll
        for (int n = 0; n < 4; ++n) acc[m][n] = (f32x4){0.f, 0.f, 0.f, 0.f};

    __syncthreads();
#pragma unroll
    for (int kk = 0; kk < 4; ++kk) {
        int so = (((kk * 4 + hk) ^ lr) << 3);
        f16x8 a[4], b[4];
#pragma unroll
        for (int m = 0; m < 4; ++m) a[m] = *(const f16x8*)(ar[m] + so);
#pragma unroll
        for (int n = 0; n < 4; ++n) b[n] = *(const f16x8*)(br[n] + so);
#pragma unroll
        for (int m = 0; m < 4; ++m)
#pragma unroll
            for (int n = 0; n < 4; ++n)
                acc[m][n] = __builtin_amdgcn_mfma_f32_16x16x32_f16(a[m], b[n], acc[m][n], 0, 0, 0);
    }
    float bias[4];
#pragma unroll
    for (int n = 0; n < 4; ++n) bias[n] = bias1[c0 + wc * 64 + n * 16 + lr];
    __syncthreads();
    f16* outT = smem;                         // [128][136]
#pragma unroll
    for (int m = 0; m < 4; ++m)
#pragma unroll
        for (int reg = 0; reg < 4; ++reg) {
            int rowL = wr * 64 + m * 16 + hk * 4 + reg;
#pragma unroll
            for (int n = 0; n < 4; ++n)
                outT[rowL * 136 + wc * 64 + n * 16 + lr] =
                    (f16)fmaxf(acc[m][n][reg] + bias[n], 0.f);
        }
    __syncthreads();
#pragma unroll
    for (int pass = 0; pass < 8; ++pass) {
        int rowL = pass * 16 + (tid >> 4);
        int sc = (tid & 15) << 3;
        f16x8 v = *(const f16x8*)(outT + rowL * 136 + sc);
        *(f16x8*)(hdn_all + (size_t)(r0 + rowL) * 1536 + c0 + sc) = v;
    }
}

// ---------------------------------------------------------------------------
// K4: single-stage Wh GEMM (K=128), 128x64 tile (48KB LDS -> 3 blocks/CU),
// into permuted whbuf. grid (64, ceil/128, 4)
// ---------------------------------------------------------------------------
__global__ __launch_bounds__(256) void gemm_wh_mfma(const f16* __restrict__ hdn_all,
                                                    const f16* __restrict__ b2t,
                                                    const float* __restrict__ wh2b,
                                                    f16* __restrict__ whbuf,
                                                    int chunk0, int chunkrows) {
    __shared__ f16 smem[24576];               // As 32KB | Bs 16KB; outT reuses As
    f16* As = smem;
    f16* Bs = smem + 16384;
    int g = blockIdx.z, col0 = blockIdx.x * 64, r0 = blockIdx.y * 128;
    int tid = threadIdx.x, w = tid >> 6;
    const f16* Ag = hdn_all + (size_t)(chunk0 + r0) * 1536 + 512 + g * 128;
    const f16* Bg = b2t + ((size_t)g * 4096 + col0) * 128;
    int srow = tid >> 4;
    int scol = ((tid & 15) ^ (srow & 15)) << 3;
#pragma unroll
    for (int j = 0; j < 8; ++j)
        GLOAD16(Ag + (size_t)(j * 16 + srow) * 1536 + scol, As + j * 2048 + w * 512);
#pragma unroll
    for (int j = 0; j < 4; ++j)
        GLOAD16(Bg + (size_t)(j * 16 + srow) * 128 + scol, Bs + j * 2048 + w * 512);

    int l = tid & 63, wr = w >> 1, wc = w & 1, lr = l & 15, hk = l >> 4;
    const f16 *ar[4], *br[2];
#pragma unroll
    for (int m = 0; m < 4; ++m) ar[m] = As + (wr * 64 + m * 16 + lr) * 128;
#pragma unroll
    for (int n = 0; n < 2; ++n) br[n] = Bs + (wc * 32 + n * 16 + lr) * 128;

    f32x4 acc[4][2];
#pragma unroll
    for (int m = 0; m < 4; ++m)
#pragma unroll
        for (int n = 0; n < 2; ++n) acc[m][n] = (f32x4){0.f, 0.f, 0.f, 0.f};

    __syncthreads();
#pragma unroll
    for (int kk = 0; kk < 4; ++kk) {
        int so = (((kk * 4 + hk) ^ lr) << 3);
        f16x8 a[4], b[2];
#pragma unroll
        for (int m = 0; m < 4; ++m) a[m] = *(const f16x8*)(ar[m] + so);
#pragma unroll
        for (int n = 0; n < 2; ++n) b[n] = *(const f16x8*)(br[n] + so);
#pragma unroll
        for (int m = 0; m < 4; ++m)
#pragma unroll
            for (int n = 0; n < 2; ++n)
                acc[m][n] = __builtin_amdgcn_mfma_f32_16x16x32_f16(a[m], b[n], acc[m][n], 0, 0, 0);
    }
    float bias[2];
#pragma unroll
    for (int n = 0; n < 2; ++n) {
        int colp = col0 + wc * 32 + n * 16 + lr;
        bias[n] = wh2b[g * 4096 + wh_perm_inv(colp)];
    }
    __syncthreads();
    f16* outT = smem;                         // [128][64], 16KB (in As region)
#pragma unroll
    for (int m = 0; m < 4; ++m)
#pragma unroll
        for (int reg = 0; reg < 4; ++reg) {
            int rowL = wr * 64 + m * 16 + hk * 4 + reg;
#pragma unroll
            for (int n = 0; n < 2; ++n)
                outT[rowL * 64 + wc * 32 + n * 16 + lr] = (f16)(acc[m][n][reg] + bias[n]);
        }
    __syncthreads();
#pragma unroll
    for (int pass = 0; pass < 4; ++pass) {
        int rowL = pass * 32 + (tid >> 3);
        int row = r0 + rowL;
        if (row < chunkrows) {
            int sc = (tid & 7) << 3;
            f16x8 v = *(const f16x8*)(outT + rowL * 64 + sc);
            *(f16x8*)(whbuf + ((size_t)row * 4 + g) * 4096 + col0 + sc) = v;
        }
    }
}

// ---------------------------------------------------------------------------
// K5: single-stage batched stage-2 GEMMs: wxbb[combo][row][64]. grid (82, 8)
// ---------------------------------------------------------------------------
__global__ __launch_bounds__(256) void stage2s_gemm(const f16* __restrict__ hdn_all,
                                                    const f16* __restrict__ b2s,
                                                    const float* __restrict__ bias2s,
                                                    float* __restrict__ wxbb) {
    __shared__ f16 smem[24576];               // As 16K | Bs 8K
    f16* As = smem;
    f16* Bs = smem + 16384;
    int combo = blockIdx.y, r0 = blockIdx.x * 128;
    int a = combo >> 2, g = combo & 3;
    int aoff = (a ? 1024 : 0) + g * 128;
    int tid = threadIdx.x, w = tid >> 6;
    const f16* Ag = hdn_all + (size_t)r0 * 1536 + aoff;
    const f16* Bg = b2s + (size_t)combo * 8192;
    int srow = tid >> 4;
    int scol = ((tid & 15) ^ (srow & 15)) << 3;
#pragma unroll
    for (int j = 0; j < 8; ++j)
        GLOAD16(Ag + (size_t)(j * 16 + srow) * 1536 + scol, As + j * 2048 + w * 512);
#pragma unroll
    for (int j = 0; j < 4; ++j)
        GLOAD16(Bg + (size_t)(j * 16 + srow) * 128 + scol, Bs + j * 2048 + w * 512);

    int l = tid & 63, lr = l & 15, hk = l >> 4;
    const f16 *ar[2], *br[4];
#pragma unroll
    for (int m = 0; m < 2; ++m) ar[m] = As + (w * 32 + m * 16 + lr) * 128;
#pragma unroll
    for (int n = 0; n < 4; ++n) br[n] = Bs + (n * 16 + lr) * 128;

    f32x4 acc[2][4];
#pragma unroll
    for (int m = 0; m < 2; ++m)
#pragma unroll
        for (int n = 0; n < 4; ++n) acc[m][n] = (f32x4){0.f, 0.f, 0.f, 0.f};

    __syncthreads();
#pragma unroll
    for (int kk = 0; kk < 4; ++kk) {
        int so = (((kk * 4 + hk) ^ lr) << 3);
        f16x8 av[2], bv[4];
#pragma unroll
        for (int m = 0; m < 2; ++m) av[m] = *(const f16x8*)(ar[m] + so);
#pragma unroll
        for (int n = 0; n < 4; ++n) bv[n] = *(const f16x8*)(br[n] + so);
#pragma unroll
        for (int m = 0; m < 2; ++m)
#pragma unroll
            for (int n = 0; n < 4; ++n)
                acc[m][n] = __builtin_amdgcn_mfma_f32_16x16x32_f16(av[m], bv[n], acc[m][n], 0, 0, 0);
    }
    float bias[4];
#pragma unroll
    for (int n = 0; n < 4; ++n) bias[n] = bias2s[combo * 64 + n * 16 + lr];
#pragma unroll
    for (int m = 0; m < 2; ++m)
#pragma unroll
        for (int reg = 0; reg < 4; ++reg) {
            int row = r0 + w * 32 + m * 16 + hk * 4 + reg;
            if (row < BN) {
#pragma unroll
                for (int n = 0; n < 4; ++n) {
                    int col = n * 16 + lr;
                    wxbb[((size_t)combo * BN + row) * 64 + col] = acc[m][n][reg] + bias[n];
                }
            }
        }
}

// ---------------------------------------------------------------------------
// K6: wave-per-row LSTM + head (zero barriers, fdot2, fast activations)
// ---------------------------------------------------------------------------
__global__ __launch_bounds__(256) void lstm_head_kernel(const f16* __restrict__ whbuf,
                                                        const float* __restrict__ wxbb,
                                                        const float* __restrict__ x,
                                                        const float* __restrict__ fc1,
                                                        const float* __restrict__ fc1b,
                                                        const float* __restrict__ fc2,
                                                        const float* __restrict__ fc2b,
                                                        float* __restrict__ out,
                                                        int chunk0, int chunkrows) {
    __shared__ __align__(16) f16 hs[4][64];
    __shared__ float xts[4][TT];
    __shared__ float a1s[4][32];
    int w = threadIdx.x >> 6, lane = threadIdx.x & 63;
    int r = blockIdx.x * 4 + w;
    if (r >= chunkrows) return;
    int row = chunk0 + r;
    int b = row / NNODE, n = row - b * NNODE;
    int k = lane;

    const f16* wp = whbuf + ((size_t)r * 4) * 4096 + k * 8;
    f16x8 wh[4][8];
#pragma unroll
    for (int g = 0; g < 4; ++g)
#pragma unroll
        for (int jj = 0; jj < 8; ++jj)
            wh[g][jj] = *(const f16x8*)(wp + (size_t)g * 4096 + jj * 512);

    float wxv[4], bbv[4];
#pragma unroll
    for (int g = 0; g < 4; ++g) {
        wxv[g] = wxbb[((size_t)g * BN + row) * HH + k];
        bbv[g] = wxbb[((size_t)(4 + g) * BN + row) * HH + k];
    }
    if (lane < TT) xts[w][lane] = x[((size_t)b * TT + lane) * NNODE * XC + (size_t)n * XC];
    hs[w][k] = (f16)0.f;

    float c = 0.f;
    for (int t = 0; t < TT; ++t) {
        float xt = xts[w][t];
        float z0 = wxv[0] * xt + bbv[0];
        float z1 = wxv[1] * xt + bbv[1];
        float z2 = wxv[2] * xt + bbv[2];
        float z3 = wxv[3] * xt + bbv[3];
#pragma unroll
        for (int jj = 0; jj < 8; ++jj) {
            f16x8 hv = ((const f16x8*)hs[w])[jj];
#pragma unroll
            for (int p = 0; p < 4; ++p) {
                f16x2 hp = {hv[2 * p], hv[2 * p + 1]};
                f16x2 w0 = {wh[0][jj][2 * p], wh[0][jj][2 * p + 1]};
                f16x2 w1 = {wh[1][jj][2 * p], wh[1][jj][2 * p + 1]};
                f16x2 w2 = {wh[2][jj][2 * p], wh[2][jj][2 * p + 1]};
                f16x2 w3 = {wh[3][jj][2 * p], wh[3][jj][2 * p + 1]};
                z0 = FDOT2(w0, hp, z0);
                z1 = FDOT2(w1, hp, z1);
                z2 = FDOT2(w2, hp, z2);
                z3 = FDOT2(w3, hp, z3);
            }
        }
        float gg = fast_tanh(z0);
        float ii = fast_sig(z1);
        float ff = fast_sig(z2);
        float oo = fast_sig(z3);
        c = gg * ii + c * ff;
        hs[w][k] = (f16)(fast_tanh(c) * oo);
    }
    if (lane < 32) {
        float s = fc1b[lane];
#pragma unroll
        for (int h = 0; h < 64; ++h)
            s += fmaxf((float)hs[w][h], 0.f) * fc1[h * 32 + lane];
        a1s[w][lane] = fmaxf(s, 0.f);
    }
    if (lane < OUTT) {
        float s = fc2b[lane];
#pragma unroll
        for (int j = 0; j < 32; ++j) s += a1s[w][j] * fc2[j * OUTT + lane];
        out[((size_t)b * OUTT + lane) * NNODE + n] = s;
    }
}

// ---------------------------------------------------------------------------
extern "C" void kernel_launch(void* const* d_in, const int* in_sizes, int n_in,
                              void* d_out, int out_size, void* d_ws, size_t ws_size,
                              hipStream_t stream) {
    (void)in_sizes; (void)n_in; (void)out_size;
    const float* x    = (const float*)d_in[0];
    const float* wx1  = (const float*)d_in[1];
    const float* wx1b = (const float*)d_in[2];
    const float* wx2  = (const float*)d_in[3];
    const float* wx2b = (const float*)d_in[4];
    const float* wh1  = (const float*)d_in[5];
    const float* wh1b = (const float*)d_in[6];
    const float* wh2  = (const float*)d_in[7];
    const float* wh2b = (const float*)d_in[8];
    const float* b1   = (const float*)d_in[9];
    const float* b1b  = (const float*)d_in[10];
    const float* b2   = (const float*)d_in[11];
    const float* b2b  = (const float*)d_in[12];
    const float* fc1  = (const float*)d_in[13];
    const float* fc1b = (const float*)d_in[14];
    const float* fc2  = (const float*)d_in[15];
    const float* fc2b = (const float*)d_in[16];
    float* out = (float*)d_out;
    float* ws  = (float*)d_ws;

    float* bias1  = ws;                              // 1,536 f
    float* bias2s = bias1 + 1536;                    // 512 f
    float* wxbb   = bias2s + 512;                    // 5,324,800 f
    f16* meta2    = (f16*)(wxbb + 5324800);          // BNP*128 = 1,343,488
    f16* B1t      = meta2 + (size_t)BNP * 128;       // 196,608
    f16* hdn_all  = B1t + 196608;                    // BNP*1536
    f16* b2t      = hdn_all + (size_t)BNP * 1536;    // 4*4096*128
    f16* b2s      = b2t + (size_t)4 * 4096 * 128;    // 65,536
    f16* whbuf    = b2s + 65536;                     // chunk*16384 (reused per chunk)

    const size_t fixedB = (size_t)(1536 + 512 + 5324800) * 4
        + ((size_t)BNP * 128 + 196608 + (size_t)BNP * 1536
           + (size_t)4 * 4096 * 128 + 65536) * 2;
    size_t availB = (ws_size > fixedB) ? (ws_size - fixedB) : 0;
    long long ch = (long long)(availB / (16384 * 2));
    if (ch > 5248) ch = 5248;   // 2 chunks: fewest serial gemm->lstm boundaries
    if (ch < 128)  ch = 128;
    int chunk = (int)(ch & ~127LL);

    meta2_kernel<<<(BNP * 128 + 255) / 256, 256, 0, stream>>>(x, meta2);
    prep_b2t_kernel<<<1544, 256, 0, stream>>>(wx1, wx1b, wx2, wx2b, wh1, wh1b,
                                              b1, b1b, b2, b2b, wh2,
                                              B1t, bias1, b2s, bias2s, b2t);
    stage1_gemm<<<dim3(12, BNP / 128), 256, 0, stream>>>(meta2, B1t, bias1, hdn_all);
    stage2s_gemm<<<dim3(BNP / 128, 8), 256, 0, stream>>>(hdn_all, b2s, bias2s, wxbb);
    for (int c0 = 0; c0 < BN; c0 += chunk) {
        int cr = BN - c0;
        if (cr > chunk) cr = chunk;
        gemm_wh_mfma<<<dim3(64, (cr + 127) / 128, 4), 256, 0, stream>>>(
            hdn_all, b2t, wh2b, whbuf, c0, cr);
        lstm_head_kernel<<<(cr + 3) / 4, 256, 0, stream>>>(whbuf, wxbb, x, fc1, fc1b,
                                                           fc2, fc2b, out, c0, cr);
    }
}